// Round 13
// baseline (601.266 us; speedup 1.0000x reference)
//
#include <hip/hip_runtime.h>

#define N_NODESC 100000
#define N_EDGESC 1600000
#define N_GRAPHSC 64
#define HIDC 128
#define NCLSC 696
#define SLOTCAP 64

typedef __attribute__((ext_vector_type(8))) short short8;
typedef __attribute__((ext_vector_type(4))) float f32x4;
typedef __attribute__((ext_vector_type(4))) int int4_t;
typedef __attribute__((ext_vector_type(2))) unsigned int uint2_t;

__device__ __forceinline__ ushort f2b(float x) {
  union { float f; unsigned u; } a; a.f = x;
  unsigned r = a.u + 0x7FFFu + ((a.u >> 16) & 1u);
  return (ushort)(r >> 16);
}
__device__ __forceinline__ float b2f(ushort b) {
  union { float f; unsigned u; } a; a.u = ((unsigned)b) << 16;
  return a.f;
}

// ---------------- adjacency build: XCD-partitioned scatter, NT streaming reads ----------------
// NT loads keep the streaming ei scan from evicting the dirty 3.2MB slot window in each XCD L2.
__global__ __launch_bounds__(256) void k_scatter_slots(const int* __restrict__ ei,
                                                       int* __restrict__ cnt,
                                                       int* __restrict__ slots, int E) {
  int xcd = blockIdx.x & 7;
  int gblk = blockIdx.x >> 3;
  int nblk = gridDim.x >> 3;
  int lo = xcd * 12500;
  int hi = (xcd == 7) ? N_NODESC : lo + 12500;
  for (int e = gblk * 256 + threadIdx.x; e < E; e += nblk * 256) {
    int dst = __builtin_nontemporal_load(ei + E + e);
    if (dst >= lo && dst < hi) {
      int src = __builtin_nontemporal_load(ei + e);
      int pos = atomicAdd(&cnt[dst], 1);
      if (pos < SLOTCAP) slots[(size_t)dst * SLOTCAP + pos] = src;
    }
  }
}

// ---------------- weight split (transpose + hi/lo bf16) ----------------
__global__ void k_wsplit(const float* __restrict__ W1s, const float* __restrict__ W2s,
                         ushort* __restrict__ hi, ushort* __restrict__ lo) {
  int idx = blockIdx.x * 256 + threadIdx.x;  // 8*16384
  if (idx >= 8 * 16384) return;
  int m = idx >> 14;
  int r = (idx >> 7) & 127;  // n (output col)
  int k = idx & 127;
  const float* W = (m < 4) ? (W1s + (size_t)m * 16384) : (W2s + (size_t)(m - 4) * 16384);
  float v = W[k * 128 + r];
  ushort vh = f2b(v);
  float res = v - b2f(vh);
  hi[idx] = vh;
  lo[idx] = f2b(res);
}

// ---------------- x -> bf16 converter ----------------
__global__ void k_tobf(const float* __restrict__ in, ushort* __restrict__ out, int n4) {
  int i = blockIdx.x * 256 + threadIdx.x;
  if (i < n4) {
    f32x4 v = ((const f32x4*)in)[i];
    uint2_t u;
    u[0] = (unsigned)f2b(v[0]) | ((unsigned)f2b(v[1]) << 16);
    u[1] = (unsigned)f2b(v[2]) | ((unsigned)f2b(v[3]) << 16);
    ((uint2_t*)out)[i] = u;
  }
}

// ---------------- aggregation (bf16 h -> bf16 z), NT on index reads + z writes ----------------
// h gathers stay cached (the reuse); slot/cnt reads and z writes are streaming -> NT.
__global__ __launch_bounds__(256) void k_aggr(const ushort* __restrict__ hbf,
                                              const int* __restrict__ cnt,
                                              const int* __restrict__ slots,
                                              ushort* __restrict__ zbf, int n_nodes) {
  int node = blockIdx.x * 4 + (threadIdx.x >> 6);
  if (node >= n_nodes) return;
  int lane = threadIdx.x & 63;
  const unsigned* base = (const unsigned*)hbf;  // row stride 64 u32
  unsigned sv = base[(size_t)node * 64 + lane];
  float accx = b2f((ushort)(sv & 0xFFFFu)), accy = b2f((ushort)(sv >> 16));
  const int* srow = slots + (size_t)node * SLOTCAP;
  int d = __builtin_nontemporal_load(cnt + node);
  if (d > SLOTCAP) d = SLOTCAP;
  int j = 0;
  for (; j + 8 <= d; j += 8) {
    int4_t s0 = __builtin_nontemporal_load((const int4_t*)&srow[j]);
    int4_t s1 = __builtin_nontemporal_load((const int4_t*)&srow[j + 4]);
    unsigned v[8];
#pragma unroll
    for (int q = 0; q < 4; ++q) {
      v[q]     = base[(size_t)s0[q] * 64 + lane];
      v[4 + q] = base[(size_t)s1[q] * 64 + lane];
    }
#pragma unroll
    for (int q = 0; q < 8; ++q) {
      accx += b2f((ushort)(v[q] & 0xFFFFu));
      accy += b2f((ushort)(v[q] >> 16));
    }
  }
  for (; j + 2 <= d; j += 2) {
    int sj0 = __builtin_nontemporal_load(srow + j);
    int sj1 = __builtin_nontemporal_load(srow + j + 1);
    unsigned v0 = base[(size_t)sj0 * 64 + lane];
    unsigned v1 = base[(size_t)sj1 * 64 + lane];
    accx += b2f((ushort)(v0 & 0xFFFFu)) + b2f((ushort)(v1 & 0xFFFFu));
    accy += b2f((ushort)(v0 >> 16)) + b2f((ushort)(v1 >> 16));
  }
  if (j < d) {
    int sj0 = __builtin_nontemporal_load(srow + j);
    unsigned v0 = base[(size_t)sj0 * 64 + lane];
    accx += b2f((ushort)(v0 & 0xFFFFu));
    accy += b2f((ushort)(v0 >> 16));
  }
  unsigned outw = (unsigned)f2b(accx) | ((unsigned)f2b(accy) << 16);
  __builtin_nontemporal_store(outw, (unsigned*)zbf + (size_t)node * 64 + lane);
}

// ---------------- fused MLP, single 17.4KB LDS buffer ----------------
__global__ __launch_bounds__(256) void k_mlp(const ushort* __restrict__ zbf,
                                             const ushort* __restrict__ W1hi,
                                             const ushort* __restrict__ W1lo,
                                             const ushort* __restrict__ W2hi,
                                             const ushort* __restrict__ W2lo,
                                             const float* __restrict__ bias1,
                                             const float* __restrict__ bias2,
                                             ushort* __restrict__ houtbf, int M) {
  __shared__ __align__(16) ushort ahi[64 * 136];  // 17408 B

  int t = threadIdx.x;
  int lane = t & 63, w = t >> 6;
  int row0 = blockIdx.x * 64;

  for (int c = t; c < 2048; c += 256) {
    int r = c >> 5;
    int c8 = c & 31;
    int gr = row0 + r;
    if (gr >= M) gr = M - 1;
    uint2_t u = ((const uint2_t*)zbf)[(size_t)gr * 32 + c8];
    *(uint2_t*)&ahi[r * 136 + c8 * 4] = u;
  }
  __syncthreads();

  int koff = (lane >> 4) * 8;
  int fr16 = lane & 15;
  int colb = lane & 15;
  int rbase = (lane >> 4) * 4;

  // GEMM1 = relu(Z @ W1 + b1)
  {
    f32x4 acc[4][2];
#pragma unroll
    for (int rg = 0; rg < 4; ++rg)
#pragma unroll
      for (int nn = 0; nn < 2; ++nn) acc[rg][nn] = (f32x4){0.f, 0.f, 0.f, 0.f};
#pragma unroll
    for (int ks = 0; ks < 4; ++ks) {
      short8 b_h[2], b_l[2];
#pragma unroll
      for (int nn = 0; nn < 2; ++nn) {
        int widx = ((w * 2 + nn) * 16 + fr16) * 128 + ks * 32 + koff;
        b_h[nn] = *(const short8*)&W1hi[widx];
        b_l[nn] = *(const short8*)&W1lo[widx];
      }
#pragma unroll
      for (int rg = 0; rg < 4; ++rg) {
        short8 a_h = *(const short8*)&ahi[(rg * 16 + fr16) * 136 + ks * 32 + koff];
#pragma unroll
        for (int nn = 0; nn < 2; ++nn) {
          acc[rg][nn] = __builtin_amdgcn_mfma_f32_16x16x32_bf16(a_h, b_h[nn], acc[rg][nn], 0, 0, 0);
          acc[rg][nn] = __builtin_amdgcn_mfma_f32_16x16x32_bf16(a_h, b_l[nn], acc[rg][nn], 0, 0, 0);
        }
      }
    }
    __syncthreads();
#pragma unroll
    for (int nn = 0; nn < 2; ++nn) {
      int col = (w * 2 + nn) * 16 + colb;
      float bv = bias1[col];
#pragma unroll
      for (int rg = 0; rg < 4; ++rg) {
#pragma unroll
        for (int r = 0; r < 4; ++r) {
          float v = fmaxf(acc[rg][nn][r] + bv, 0.f);
          ahi[(rg * 16 + rbase + r) * 136 + col] = f2b(v);
        }
      }
    }
  }
  __syncthreads();

  // GEMM2 = relu(C1 @ W2 + b2)
  {
    f32x4 acc[4][2];
#pragma unroll
    for (int rg = 0; rg < 4; ++rg)
#pragma unroll
      for (int nn = 0; nn < 2; ++nn) acc[rg][nn] = (f32x4){0.f, 0.f, 0.f, 0.f};
#pragma unroll
    for (int ks = 0; ks < 4; ++ks) {
      short8 b_h[2], b_l[2];
#pragma unroll
      for (int nn = 0; nn < 2; ++nn) {
        int widx = ((w * 2 + nn) * 16 + fr16) * 128 + ks * 32 + koff;
        b_h[nn] = *(const short8*)&W2hi[widx];
        b_l[nn] = *(const short8*)&W2lo[widx];
      }
#pragma unroll
      for (int rg = 0; rg < 4; ++rg) {
        short8 a_h = *(const short8*)&ahi[(rg * 16 + fr16) * 136 + ks * 32 + koff];
#pragma unroll
        for (int nn = 0; nn < 2; ++nn) {
          acc[rg][nn] = __builtin_amdgcn_mfma_f32_16x16x32_bf16(a_h, b_h[nn], acc[rg][nn], 0, 0, 0);
          acc[rg][nn] = __builtin_amdgcn_mfma_f32_16x16x32_bf16(a_h, b_l[nn], acc[rg][nn], 0, 0, 0);
        }
      }
    }
    __syncthreads();
#pragma unroll
    for (int nn = 0; nn < 2; ++nn) {
      int col = (w * 2 + nn) * 16 + colb;
      float bv = bias2[col];
#pragma unroll
      for (int rg = 0; rg < 4; ++rg) {
#pragma unroll
        for (int r = 0; r < 4; ++r) {
          float v = fmaxf(acc[rg][nn][r] + bv, 0.f);
          ahi[(rg * 16 + rbase + r) * 136 + col] = f2b(v);
        }
      }
    }
  }
  __syncthreads();

  for (int c = t; c < 2048; c += 256) {
    int r = c >> 5;
    int c8 = c & 31;
    int gr = row0 + r;
    if (gr < M) {
      uint2_t u = *(const uint2_t*)&ahi[r * 136 + c8 * 4];
      ((uint2_t*)houtbf)[(size_t)gr * 32 + c8] = u;
    }
  }
}

// ---------------- global add pool (bf16 h) ----------------
__global__ __launch_bounds__(256) void k_pool(const ushort* __restrict__ h,
                                              const int* __restrict__ batch,
                                              float* __restrict__ g, int n_nodes) {
  int wave = (blockIdx.x * 256 + threadIdx.x) >> 6;
  int lane = threadIdx.x & 63;
  int n0 = wave * 64;
  if (n0 >= n_nodes) return;
  int n1 = n0 + 64;
  if (n1 > n_nodes) n1 = n_nodes;
  const unsigned* base = (const unsigned*)h;
  float accx = 0.f, accy = 0.f;
  int curg = batch[n0];
  int lastg = batch[n1 - 1];
  if (curg == lastg) {
    int n = n0;
    for (; n + 4 <= n1; n += 4) {
      unsigned v0 = base[(size_t)n * 64 + lane];
      unsigned v1 = base[(size_t)(n + 1) * 64 + lane];
      unsigned v2 = base[(size_t)(n + 2) * 64 + lane];
      unsigned v3 = base[(size_t)(n + 3) * 64 + lane];
      accx += (b2f((ushort)(v0 & 0xFFFFu)) + b2f((ushort)(v1 & 0xFFFFu))) +
              (b2f((ushort)(v2 & 0xFFFFu)) + b2f((ushort)(v3 & 0xFFFFu)));
      accy += (b2f((ushort)(v0 >> 16)) + b2f((ushort)(v1 >> 16))) +
              (b2f((ushort)(v2 >> 16)) + b2f((ushort)(v3 >> 16)));
    }
    for (; n < n1; ++n) {
      unsigned v = base[(size_t)n * 64 + lane];
      accx += b2f((ushort)(v & 0xFFFFu));
      accy += b2f((ushort)(v >> 16));
    }
    atomicAdd(&g[curg * 128 + 2 * lane], accx);
    atomicAdd(&g[curg * 128 + 2 * lane + 1], accy);
  } else {
    for (int n = n0; n < n1; ++n) {
      int b = batch[n];
      if (b != curg) {
        atomicAdd(&g[curg * 128 + 2 * lane], accx);
        atomicAdd(&g[curg * 128 + 2 * lane + 1], accy);
        accx = 0.f; accy = 0.f; curg = b;
      }
      unsigned v = base[(size_t)n * 64 + lane];
      accx += b2f((ushort)(v & 0xFFFFu));
      accy += b2f((ushort)(v >> 16));
    }
    atomicAdd(&g[curg * 128 + 2 * lane], accx);
    atomicAdd(&g[curg * 128 + 2 * lane + 1], accy);
  }
}

// ---------------- head: fc1+relu, fc2, log_softmax ----------------
__global__ __launch_bounds__(128) void k_head(const float* __restrict__ g,
                                              const float* __restrict__ fc1w,
                                              const float* __restrict__ fc1b,
                                              const float* __restrict__ fc2w,
                                              const float* __restrict__ fc2b,
                                              float* __restrict__ out) {
  __shared__ float gs[128], a1[128], lg[696];
  __shared__ float wred[2];
  int gr = blockIdx.x, t = threadIdx.x;
  gs[t] = g[gr * 128 + t];
  __syncthreads();
  float acc = fc1b[t];
  for (int k = 0; k < 128; ++k) acc += gs[k] * fc1w[k * 128 + t];
  a1[t] = fmaxf(acc, 0.f);
  __syncthreads();
  for (int c = t; c < 696; c += 128) {
    float s = fc2b[c];
    for (int k = 0; k < 128; ++k) s += a1[k] * fc2w[k * 696 + c];
    lg[c] = s;
  }
  __syncthreads();
  float m = -__builtin_inff();
  for (int c = t; c < 696; c += 128) m = fmaxf(m, lg[c]);
  for (int d = 32; d; d >>= 1) m = fmaxf(m, __shfl_xor(m, d, 64));
  if ((t & 63) == 0) wred[t >> 6] = m;
  __syncthreads();
  m = fmaxf(wred[0], wred[1]);
  __syncthreads();
  float se = 0.f;
  for (int c = t; c < 696; c += 128) se += expf(lg[c] - m);
  for (int d = 32; d; d >>= 1) se += __shfl_xor(se, d, 64);
  __shared__ float wred2[2];
  if ((t & 63) == 0) wred2[t >> 6] = se;
  __syncthreads();
  float lse = m + logf(wred2[0] + wred2[1]);
  for (int c = t; c < 696; c += 128) out[gr * 696 + c] = lg[c] - lse;
}

extern "C" void kernel_launch(void* const* d_in, const int* in_sizes, int n_in,
                              void* d_out, int out_size, void* d_ws, size_t ws_size,
                              hipStream_t stream) {
  const float* x    = (const float*)d_in[0];
  const int*   ei   = (const int*)d_in[1];
  const int*   batch= (const int*)d_in[2];
  const float* W1s  = (const float*)d_in[3];
  const float* b1s  = (const float*)d_in[4];
  const float* W2s  = (const float*)d_in[5];
  const float* b2s  = (const float*)d_in[6];
  const float* fc1w = (const float*)d_in[7];
  const float* fc1b = (const float*)d_in[8];
  const float* fc2w = (const float*)d_in[9];
  const float* fc2b = (const float*)d_in[10];
  float* out = (float*)d_out;

  char* ws = (char*)d_ws;
  size_t off = 0;
  auto alloc = [&](size_t bytes) -> void* {
    void* p = ws + off;
    off = (off + bytes + 255) & ~(size_t)255;
    return p;
  };
  ushort* zbf   = (ushort*)alloc((size_t)N_NODESC * 128 * 2);
  ushort* xbf   = (ushort*)alloc((size_t)N_NODESC * 128 * 2);
  ushort* hbfA  = (ushort*)alloc((size_t)N_NODESC * 128 * 2);
  ushort* hbfB  = (ushort*)alloc((size_t)N_NODESC * 128 * 2);
  int*    slots = (int*)alloc((size_t)N_NODESC * SLOTCAP * 4);
  int*    cnt   = (int*)alloc((size_t)N_NODESC * 4);
  float*  g     = (float*)alloc(64 * 128 * 4);
  ushort* wthi  = (ushort*)alloc((size_t)8 * 16384 * 2);
  ushort* wtlo  = (ushort*)alloc((size_t)8 * 16384 * 2);

  // adjacency: one memset + XCD-partitioned scatter (NT streaming reads)
  hipMemsetAsync(cnt, 0, (size_t)N_NODESC * 4, stream);
  k_scatter_slots<<<dim3(2048), dim3(256), 0, stream>>>(ei, cnt, slots, N_EDGESC);

  // preprocessing: weights split, x -> bf16
  k_wsplit<<<dim3(512), dim3(256), 0, stream>>>(W1s, W2s, wthi, wtlo);
  k_tobf<<<dim3((N_NODESC * 32 + 255) / 256), dim3(256), 0, stream>>>(x, xbf, N_NODESC * 32);

  // 4 GIN layers
  const int NBLK = (N_NODESC + 63) / 64;  // 1563
  const ushort* hin = xbf;
  ushort* houts[4] = {hbfA, hbfB, hbfA, hbfB};
  for (int L = 0; L < 4; ++L) {
    ushort* hout = houts[L];
    k_aggr<<<dim3((N_NODESC + 3) / 4), dim3(256), 0, stream>>>(hin, cnt, slots, zbf, N_NODESC);
    k_mlp<<<dim3(NBLK), dim3(256), 0, stream>>>(
        zbf, wthi + (size_t)L * 16384, wtlo + (size_t)L * 16384,
        wthi + (size_t)(4 + L) * 16384, wtlo + (size_t)(4 + L) * 16384,
        b1s + L * 128, b2s + L * 128, hout, N_NODESC);
    hin = hout;
  }

  // pool + head
  hipMemsetAsync(g, 0, 64 * 128 * 4, stream);
  k_pool<<<dim3((N_NODESC + 255) / 256), dim3(256), 0, stream>>>(hbfB, batch, g, N_NODESC);
  k_head<<<dim3(64), dim3(128), 0, stream>>>(g, fc1w, fc1b, fc2w, fc2b, out);
}

// Round 14
// 516.260 us; speedup vs baseline: 1.1647x; 1.1647x over previous
//
#include <hip/hip_runtime.h>

#define N_NODESC 100000
#define N_EDGESC 1600000
#define N_GRAPHSC 64
#define HIDC 128
#define NCLSC 696
#define SLOTCAP 64

typedef __attribute__((ext_vector_type(8))) short short8;
typedef __attribute__((ext_vector_type(4))) float f32x4;
typedef __attribute__((ext_vector_type(2))) unsigned int uint2_t;

__device__ __forceinline__ ushort f2b(float x) {
  union { float f; unsigned u; } a; a.f = x;
  unsigned r = a.u + 0x7FFFu + ((a.u >> 16) & 1u);
  return (ushort)(r >> 16);
}
__device__ __forceinline__ float b2f(ushort b) {
  union { float f; unsigned u; } a; a.u = ((unsigned)b) << 16;
  return a.f;
}

// ---------------- adjacency build: XCD-partitioned scatter (plain loads; NT hurt, R13) ----------------
__global__ __launch_bounds__(256) void k_scatter_slots(const int* __restrict__ ei,
                                                       int* __restrict__ cnt,
                                                       int* __restrict__ slots, int E) {
  int xcd = blockIdx.x & 7;
  int gblk = blockIdx.x >> 3;
  int nblk = gridDim.x >> 3;
  int lo = xcd * 12500;
  int hi = (xcd == 7) ? N_NODESC : lo + 12500;
  for (int e = gblk * 256 + threadIdx.x; e < E; e += nblk * 256) {
    int dst = ei[E + e];
    if (dst >= lo && dst < hi) {
      int src = ei[e];
      int pos = atomicAdd(&cnt[dst], 1);
      if (pos < SLOTCAP) slots[(size_t)dst * SLOTCAP + pos] = src;
    }
  }
}

// ---------------- weight split (transpose + hi/lo bf16) ----------------
__global__ void k_wsplit(const float* __restrict__ W1s, const float* __restrict__ W2s,
                         ushort* __restrict__ hi, ushort* __restrict__ lo) {
  int idx = blockIdx.x * 256 + threadIdx.x;  // 8*16384
  if (idx >= 8 * 16384) return;
  int m = idx >> 14;
  int r = (idx >> 7) & 127;  // n (output col)
  int k = idx & 127;
  const float* W = (m < 4) ? (W1s + (size_t)m * 16384) : (W2s + (size_t)(m - 4) * 16384);
  float v = W[k * 128 + r];
  ushort vh = f2b(v);
  float res = v - b2f(vh);
  hi[idx] = vh;
  lo[idx] = f2b(res);
}

// ---------------- x -> bf16 converter ----------------
__global__ void k_tobf(const float* __restrict__ in, ushort* __restrict__ out, int n4) {
  int i = blockIdx.x * 256 + threadIdx.x;
  if (i < n4) {
    f32x4 v = ((const f32x4*)in)[i];
    uint2_t u;
    u[0] = (unsigned)f2b(v[0]) | ((unsigned)f2b(v[1]) << 16);
    u[1] = (unsigned)f2b(v[2]) | ((unsigned)f2b(v[3]) << 16);
    ((uint2_t*)out)[i] = u;
  }
}

// ---------------- aggregation (bf16 h -> bf16 z): R10 form (1 node/wave, plain loads) ----------------
__global__ __launch_bounds__(256) void k_aggr(const ushort* __restrict__ hbf,
                                              const int* __restrict__ cnt,
                                              const int* __restrict__ slots,
                                              ushort* __restrict__ zbf, int n_nodes) {
  int node = blockIdx.x * 4 + (threadIdx.x >> 6);
  if (node >= n_nodes) return;
  int lane = threadIdx.x & 63;
  const unsigned* base = (const unsigned*)hbf;  // row stride 64 u32
  unsigned sv = base[(size_t)node * 64 + lane];
  float accx = b2f((ushort)(sv & 0xFFFFu)), accy = b2f((ushort)(sv >> 16));
  const int* srow = slots + (size_t)node * SLOTCAP;
  int d = cnt[node];
  if (d > SLOTCAP) d = SLOTCAP;
  int j = 0;
  for (; j + 8 <= d; j += 8) {
    int s[8];
#pragma unroll
    for (int q = 0; q < 8; ++q) s[q] = srow[j + q];
    unsigned v[8];
#pragma unroll
    for (int q = 0; q < 8; ++q) v[q] = base[(size_t)s[q] * 64 + lane];
#pragma unroll
    for (int q = 0; q < 8; ++q) {
      accx += b2f((ushort)(v[q] & 0xFFFFu));
      accy += b2f((ushort)(v[q] >> 16));
    }
  }
  for (; j + 2 <= d; j += 2) {
    unsigned v0 = base[(size_t)srow[j] * 64 + lane];
    unsigned v1 = base[(size_t)srow[j + 1] * 64 + lane];
    accx += b2f((ushort)(v0 & 0xFFFFu)) + b2f((ushort)(v1 & 0xFFFFu));
    accy += b2f((ushort)(v0 >> 16)) + b2f((ushort)(v1 >> 16));
  }
  if (j < d) {
    unsigned v0 = base[(size_t)srow[j] * 64 + lane];
    accx += b2f((ushort)(v0 & 0xFFFFu));
    accy += b2f((ushort)(v0 >> 16));
  }
  ((unsigned*)zbf)[(size_t)node * 64 + lane] =
      (unsigned)f2b(accx) | ((unsigned)f2b(accy) << 16);
}

// ---------------- fused MLP, 128-row tile (W L2 traffic halved vs 64-row) ----------------
// col-split waves: wave w owns cols [w*32, w*32+32) over all 128 rows (rg=8 row-groups)
__global__ __launch_bounds__(256) void k_mlp(const ushort* __restrict__ zbf,
                                             const ushort* __restrict__ W1hi,
                                             const ushort* __restrict__ W1lo,
                                             const ushort* __restrict__ W2hi,
                                             const ushort* __restrict__ W2lo,
                                             const float* __restrict__ bias1,
                                             const float* __restrict__ bias2,
                                             ushort* __restrict__ houtbf, int M) {
  __shared__ __align__(16) ushort ahi[128 * 136];  // 34816 B

  int t = threadIdx.x;
  int lane = t & 63, w = t >> 6;
  int row0 = blockIdx.x * 128;

  // stage z tile (bf16) -> ahi
  for (int c = t; c < 4096; c += 256) {
    int r = c >> 5;         // 128 rows x 32 uint2-chunks
    int c8 = c & 31;
    int gr = row0 + r;
    if (gr >= M) gr = M - 1;
    uint2_t u = ((const uint2_t*)zbf)[(size_t)gr * 32 + c8];
    *(uint2_t*)&ahi[r * 136 + c8 * 4] = u;
  }
  __syncthreads();

  int koff = (lane >> 4) * 8;
  int fr16 = lane & 15;
  int colb = lane & 15;
  int rbase = (lane >> 4) * 4;

  // GEMM1 = relu(Z @ W1 + b1), C1 stored plain bf16 in place
  {
    f32x4 acc[8][2];
#pragma unroll
    for (int rg = 0; rg < 8; ++rg)
#pragma unroll
      for (int nn = 0; nn < 2; ++nn) acc[rg][nn] = (f32x4){0.f, 0.f, 0.f, 0.f};
#pragma unroll
    for (int ks = 0; ks < 4; ++ks) {
      short8 b_h[2], b_l[2];
#pragma unroll
      for (int nn = 0; nn < 2; ++nn) {
        int widx = ((w * 2 + nn) * 16 + fr16) * 128 + ks * 32 + koff;
        b_h[nn] = *(const short8*)&W1hi[widx];
        b_l[nn] = *(const short8*)&W1lo[widx];
      }
#pragma unroll
      for (int rg = 0; rg < 8; ++rg) {
        short8 a_h = *(const short8*)&ahi[(rg * 16 + fr16) * 136 + ks * 32 + koff];
#pragma unroll
        for (int nn = 0; nn < 2; ++nn) {
          acc[rg][nn] = __builtin_amdgcn_mfma_f32_16x16x32_bf16(a_h, b_h[nn], acc[rg][nn], 0, 0, 0);
          acc[rg][nn] = __builtin_amdgcn_mfma_f32_16x16x32_bf16(a_h, b_l[nn], acc[rg][nn], 0, 0, 0);
        }
      }
    }
    __syncthreads();
#pragma unroll
    for (int nn = 0; nn < 2; ++nn) {
      int col = (w * 2 + nn) * 16 + colb;
      float bv = bias1[col];
#pragma unroll
      for (int rg = 0; rg < 8; ++rg) {
#pragma unroll
        for (int r = 0; r < 4; ++r) {
          float v = fmaxf(acc[rg][nn][r] + bv, 0.f);
          ahi[(rg * 16 + rbase + r) * 136 + col] = f2b(v);
        }
      }
    }
  }
  __syncthreads();

  // GEMM2 = relu(C1 @ W2 + b2), output bf16 in place
  {
    f32x4 acc[8][2];
#pragma unroll
    for (int rg = 0; rg < 8; ++rg)
#pragma unroll
      for (int nn = 0; nn < 2; ++nn) acc[rg][nn] = (f32x4){0.f, 0.f, 0.f, 0.f};
#pragma unroll
    for (int ks = 0; ks < 4; ++ks) {
      short8 b_h[2], b_l[2];
#pragma unroll
      for (int nn = 0; nn < 2; ++nn) {
        int widx = ((w * 2 + nn) * 16 + fr16) * 128 + ks * 32 + koff;
        b_h[nn] = *(const short8*)&W2hi[widx];
        b_l[nn] = *(const short8*)&W2lo[widx];
      }
#pragma unroll
      for (int rg = 0; rg < 8; ++rg) {
        short8 a_h = *(const short8*)&ahi[(rg * 16 + fr16) * 136 + ks * 32 + koff];
#pragma unroll
        for (int nn = 0; nn < 2; ++nn) {
          acc[rg][nn] = __builtin_amdgcn_mfma_f32_16x16x32_bf16(a_h, b_h[nn], acc[rg][nn], 0, 0, 0);
          acc[rg][nn] = __builtin_amdgcn_mfma_f32_16x16x32_bf16(a_h, b_l[nn], acc[rg][nn], 0, 0, 0);
        }
      }
    }
    __syncthreads();
#pragma unroll
    for (int nn = 0; nn < 2; ++nn) {
      int col = (w * 2 + nn) * 16 + colb;
      float bv = bias2[col];
#pragma unroll
      for (int rg = 0; rg < 8; ++rg) {
#pragma unroll
        for (int r = 0; r < 4; ++r) {
          float v = fmaxf(acc[rg][nn][r] + bv, 0.f);
          ahi[(rg * 16 + rbase + r) * 136 + col] = f2b(v);
        }
      }
    }
  }
  __syncthreads();

  // coalesced bf16 store
  for (int c = t; c < 4096; c += 256) {
    int r = c >> 5;
    int c8 = c & 31;
    int gr = row0 + r;
    if (gr < M) {
      uint2_t u = *(const uint2_t*)&ahi[r * 136 + c8 * 4];
      ((uint2_t*)houtbf)[(size_t)gr * 32 + c8] = u;
    }
  }
}

// ---------------- global add pool (bf16 h) ----------------
__global__ __launch_bounds__(256) void k_pool(const ushort* __restrict__ h,
                                              const int* __restrict__ batch,
                                              float* __restrict__ g, int n_nodes) {
  int wave = (blockIdx.x * 256 + threadIdx.x) >> 6;
  int lane = threadIdx.x & 63;
  int n0 = wave * 64;
  if (n0 >= n_nodes) return;
  int n1 = n0 + 64;
  if (n1 > n_nodes) n1 = n_nodes;
  const unsigned* base = (const unsigned*)h;
  float accx = 0.f, accy = 0.f;
  int curg = batch[n0];
  int lastg = batch[n1 - 1];
  if (curg == lastg) {
    int n = n0;
    for (; n + 4 <= n1; n += 4) {
      unsigned v0 = base[(size_t)n * 64 + lane];
      unsigned v1 = base[(size_t)(n + 1) * 64 + lane];
      unsigned v2 = base[(size_t)(n + 2) * 64 + lane];
      unsigned v3 = base[(size_t)(n + 3) * 64 + lane];
      accx += (b2f((ushort)(v0 & 0xFFFFu)) + b2f((ushort)(v1 & 0xFFFFu))) +
              (b2f((ushort)(v2 & 0xFFFFu)) + b2f((ushort)(v3 & 0xFFFFu)));
      accy += (b2f((ushort)(v0 >> 16)) + b2f((ushort)(v1 >> 16))) +
              (b2f((ushort)(v2 >> 16)) + b2f((ushort)(v3 >> 16)));
    }
    for (; n < n1; ++n) {
      unsigned v = base[(size_t)n * 64 + lane];
      accx += b2f((ushort)(v & 0xFFFFu));
      accy += b2f((ushort)(v >> 16));
    }
    atomicAdd(&g[curg * 128 + 2 * lane], accx);
    atomicAdd(&g[curg * 128 + 2 * lane + 1], accy);
  } else {
    for (int n = n0; n < n1; ++n) {
      int b = batch[n];
      if (b != curg) {
        atomicAdd(&g[curg * 128 + 2 * lane], accx);
        atomicAdd(&g[curg * 128 + 2 * lane + 1], accy);
        accx = 0.f; accy = 0.f; curg = b;
      }
      unsigned v = base[(size_t)n * 64 + lane];
      accx += b2f((ushort)(v & 0xFFFFu));
      accy += b2f((ushort)(v >> 16));
    }
    atomicAdd(&g[curg * 128 + 2 * lane], accx);
    atomicAdd(&g[curg * 128 + 2 * lane + 1], accy);
  }
}

// ---------------- head: fc1+relu, fc2, log_softmax ----------------
__global__ __launch_bounds__(128) void k_head(const float* __restrict__ g,
                                              const float* __restrict__ fc1w,
                                              const float* __restrict__ fc1b,
                                              const float* __restrict__ fc2w,
                                              const float* __restrict__ fc2b,
                                              float* __restrict__ out) {
  __shared__ float gs[128], a1[128], lg[696];
  __shared__ float wred[2];
  int gr = blockIdx.x, t = threadIdx.x;
  gs[t] = g[gr * 128 + t];
  __syncthreads();
  float acc = fc1b[t];
  for (int k = 0; k < 128; ++k) acc += gs[k] * fc1w[k * 128 + t];
  a1[t] = fmaxf(acc, 0.f);
  __syncthreads();
  for (int c = t; c < 696; c += 128) {
    float s = fc2b[c];
    for (int k = 0; k < 128; ++k) s += a1[k] * fc2w[k * 696 + c];
    lg[c] = s;
  }
  __syncthreads();
  float m = -__builtin_inff();
  for (int c = t; c < 696; c += 128) m = fmaxf(m, lg[c]);
  for (int d = 32; d; d >>= 1) m = fmaxf(m, __shfl_xor(m, d, 64));
  if ((t & 63) == 0) wred[t >> 6] = m;
  __syncthreads();
  m = fmaxf(wred[0], wred[1]);
  __syncthreads();
  float se = 0.f;
  for (int c = t; c < 696; c += 128) se += expf(lg[c] - m);
  for (int d = 32; d; d >>= 1) se += __shfl_xor(se, d, 64);
  __shared__ float wred2[2];
  if ((t & 63) == 0) wred2[t >> 6] = se;
  __syncthreads();
  float lse = m + logf(wred2[0] + wred2[1]);
  for (int c = t; c < 696; c += 128) out[gr * 696 + c] = lg[c] - lse;
}

extern "C" void kernel_launch(void* const* d_in, const int* in_sizes, int n_in,
                              void* d_out, int out_size, void* d_ws, size_t ws_size,
                              hipStream_t stream) {
  const float* x    = (const float*)d_in[0];
  const int*   ei   = (const int*)d_in[1];
  const int*   batch= (const int*)d_in[2];
  const float* W1s  = (const float*)d_in[3];
  const float* b1s  = (const float*)d_in[4];
  const float* W2s  = (const float*)d_in[5];
  const float* b2s  = (const float*)d_in[6];
  const float* fc1w = (const float*)d_in[7];
  const float* fc1b = (const float*)d_in[8];
  const float* fc2w = (const float*)d_in[9];
  const float* fc2b = (const float*)d_in[10];
  float* out = (float*)d_out;

  char* ws = (char*)d_ws;
  size_t off = 0;
  auto alloc = [&](size_t bytes) -> void* {
    void* p = ws + off;
    off = (off + bytes + 255) & ~(size_t)255;
    return p;
  };
  ushort* zbf   = (ushort*)alloc((size_t)N_NODESC * 128 * 2);
  ushort* xbf   = (ushort*)alloc((size_t)N_NODESC * 128 * 2);
  ushort* hbfA  = (ushort*)alloc((size_t)N_NODESC * 128 * 2);
  ushort* hbfB  = (ushort*)alloc((size_t)N_NODESC * 128 * 2);
  int*    slots = (int*)alloc((size_t)N_NODESC * SLOTCAP * 4);
  int*    cnt   = (int*)alloc((size_t)N_NODESC * 4);
  float*  g     = (float*)alloc(64 * 128 * 4);
  ushort* wthi  = (ushort*)alloc((size_t)8 * 16384 * 2);
  ushort* wtlo  = (ushort*)alloc((size_t)8 * 16384 * 2);

  // adjacency: one memset + XCD-partitioned scatter
  hipMemsetAsync(cnt, 0, (size_t)N_NODESC * 4, stream);
  k_scatter_slots<<<dim3(2048), dim3(256), 0, stream>>>(ei, cnt, slots, N_EDGESC);

  // preprocessing: weights split, x -> bf16
  k_wsplit<<<dim3(512), dim3(256), 0, stream>>>(W1s, W2s, wthi, wtlo);
  k_tobf<<<dim3((N_NODESC * 32 + 255) / 256), dim3(256), 0, stream>>>(x, xbf, N_NODESC * 32);

  // 4 GIN layers
  const int NBLK = (N_NODESC + 127) / 128;  // 782
  const ushort* hin = xbf;
  ushort* houts[4] = {hbfA, hbfB, hbfA, hbfB};
  for (int L = 0; L < 4; ++L) {
    ushort* hout = houts[L];
    k_aggr<<<dim3((N_NODESC + 3) / 4), dim3(256), 0, stream>>>(hin, cnt, slots, zbf, N_NODESC);
    k_mlp<<<dim3(NBLK), dim3(256), 0, stream>>>(
        zbf, wthi + (size_t)L * 16384, wtlo + (size_t)L * 16384,
        wthi + (size_t)(4 + L) * 16384, wtlo + (size_t)(4 + L) * 16384,
        b1s + L * 128, b2s + L * 128, hout, N_NODESC);
    hin = hout;
  }

  // pool + head
  hipMemsetAsync(g, 0, 64 * 128 * 4, stream);
  k_pool<<<dim3((N_NODESC + 255) / 256), dim3(256), 0, stream>>>(hbfB, batch, g, N_NODESC);
  k_head<<<dim3(64), dim3(128), 0, stream>>>(g, fc1w, fc1b, fc2w, fc2b, out);
}